// Round 3
// baseline (3503.835 us; speedup 1.0000x reference)
//
#include <hip/hip_runtime.h>
#include <math.h>

#define N 64
#define LDC 68            // As leading dim (col-major); 68%32=4 spreads Cholesky banks
#define MAX_SWEEPS 10
#define SKIP_TOL2 9e-12f  // skip rotation if gamma^2 <= tol2 * a * b

// Raw-hardware approximations (~22-bit): fine for rotation params; final
// eigenvalues recomputed exactly from column norms.
__device__ __forceinline__ float frcp(float x)   { return __builtin_amdgcn_rcpf(x); }
__device__ __forceinline__ float fsqrt_(float x) { return __builtin_amdgcn_sqrtf(x); }
__device__ __forceinline__ float frsq(float x)   { return __builtin_amdgcn_rsqf(x); }
__device__ __forceinline__ float flog_(float x)  { return __builtin_amdgcn_logf(x) * 0.69314718056f; }

// Crossbar lane gather: pull a float from lane (idx>>2). No LDS banks involved.
__device__ __forceinline__ float bperm(int idx, float v) {
    return __int_as_float(__builtin_amdgcn_ds_bpermute(idx, __float_as_int(v)));
}

__global__ __launch_bounds__(64, 2)
void logeig_kernel(const float* __restrict__ P, float* __restrict__ Out) {
    __shared__ float As[N * LDC];   // col-major staging: load, Cholesky, epilogue
    __shared__ float lw_s[N];       // log(lambda)/lambda per column

    const int t = threadIdx.x;      // lane 0..63 == my column index
    const int bid = blockIdx.x;
    const float* A0 = P + (size_t)bid * (N * N);
    float* O = Out + (size_t)bid * (N * N);

    // ---- Load P (symmetric: col c == row c), fully coalesced float4. ----
    {
        const float4* A4 = (const float4*)A0;
        #pragma unroll
        for (int kk = 0; kk < 16; ++kk) {
            int f = kk * 64 + t;            // float4 index in [0,1024)
            float4 v = A4[f];
            int e = f << 2;
            int r = e >> 6;                 // row of P = dest column
            int i = e & 63;
            *(float4*)&As[r * LDC + i] = v;
        }
    }
    __syncthreads();

    // ---- Cholesky P = L L^T in place, lower triangle, col-major. ----
    for (int k = 0; k < N; ++k) {
        float dval = fmaxf(As[k * LDC + k], 1e-20f);
        float dinv = frsq(dval);
        {
            int i = k + 1 + t;
            if (i < N) As[k * LDC + i] *= dinv;
        }
        if (t == 0) As[k * LDC + k] = dval * dinv;   // = sqrt(dval)
        __syncthreads();
        for (int j = k + 1 + (t >> 3); j < N; j += 8) {
            float ljk = As[k * LDC + j];
            for (int i = j + (t & 7); i < N; i += 8)
                As[j * LDC + i] = fmaf(-As[k * LDC + i], ljk, As[j * LDC + i]);
        }
        __syncthreads();
    }

    // ---- Zero strict upper triangle (stale P entries). ----
    for (int f = t; f < N * N; f += 64) {
        int cc = f >> 6, i = f & 63;
        if (i < cc) As[cc * LDC + i] = 0.f;
    }
    __syncthreads();

    // ---- Distribute: lane c takes column c into registers. ----
    float own[N];
    #pragma unroll
    for (int i4 = 0; i4 < 16; ++i4) {
        float4 v = *(const float4*)&As[t * LDC + 4 * i4];
        own[4 * i4 + 0] = v.x;
        own[4 * i4 + 1] = v.y;
        own[4 * i4 + 2] = v.z;
        own[4 * i4 + 3] = v.w;
    }
    float nrm;
    {
        float d0 = 0.f, d1 = 0.f, d2 = 0.f, d3 = 0.f;
        #pragma unroll
        for (int i = 0; i < N; i += 4) {
            d0 = fmaf(own[i + 0], own[i + 0], d0);
            d1 = fmaf(own[i + 1], own[i + 1], d1);
            d2 = fmaf(own[i + 2], own[i + 2], d2);
            d3 = fmaf(own[i + 3], own[i + 3], d3);
        }
        nrm = (d0 + d1) + (d2 + d3);
    }

    // ---- One-sided Jacobi: column-per-lane, partner via crossbar bpermute.
    // Round r pairs: (63, r) and (r+k, r-k) mod 63. Lane c's partner:
    // c==63 -> r;  c==r -> 63;  else (2r - c) mod 63.
    // Both partners compute bit-identical gamma/params -> consistent rotation.
    // No LDS data traffic, no barriers: wave-synchronous.
    int conv = 0;
    #pragma unroll 1
    for (int sweep = 0; sweep < MAX_SWEEPS && !conv; ++sweep) {
        int rot = 0;
        #pragma unroll 1
        for (int r = 0; r < 63; ++r) {
            int pl;
            bool top;
            if (t == 63)     { pl = r;  top = true;  }
            else if (t == r) { pl = 63; top = false; }
            else {
                pl = 2 * r - t;
                if (pl < 0) pl += 63; else if (pl >= 63) pl -= 63;
                int d = t - r; if (d < 0) d += 63;
                top = (d <= 31);
            }
            int idx = pl << 2;
            float bn = bperm(idx, nrm);          // partner's norm
            float prt[N];
            #pragma unroll
            for (int i = 0; i < N; ++i) prt[i] = bperm(idx, own[i]);
            // gamma = own . partner (full dot in-lane, 4-way ILP chains)
            float d0 = 0.f, d1 = 0.f, d2 = 0.f, d3 = 0.f;
            #pragma unroll
            for (int i = 0; i < N; i += 4) {
                d0 = fmaf(own[i + 0], prt[i + 0], d0);
                d1 = fmaf(own[i + 1], prt[i + 1], d1);
                d2 = fmaf(own[i + 2], prt[i + 2], d2);
                d3 = fmaf(own[i + 3], prt[i + 3], d3);
            }
            float gd = (d0 + d1) + (d2 + d3);
            float a = top ? nrm : bn;            // ||top column||^2
            float b = top ? bn : nrm;            // ||bottom column||^2
            if (gd * gd > SKIP_TOL2 * a * b) {
                float tau = (b - a) * 0.5f * frcp(gd);
                float tt = frcp(fabsf(tau) + fsqrt_(fmaf(tau, tau, 1.f)));
                if (tau < 0.f) tt = -tt;
                float c = frsq(fmaf(tt, tt, 1.f));
                float s = tt * c;
                float sg = top ? -s : s;         // top: c*p - s*q ; bottom: s*p + c*q
                #pragma unroll
                for (int i = 0; i < N; ++i)
                    own[i] = fmaf(sg, prt[i], c * own[i]);
                float tsg = top ? -tt : tt;      // exact norm update identities
                nrm = fmaf(tsg, gd, nrm);
                rot = 1;
            }
        }
        conv = !__any(rot);
    }

    // ---- Writeback rotated columns; exact eigenvalues from column norms. ----
    #pragma unroll
    for (int i4 = 0; i4 < 16; ++i4) {
        float4 v = make_float4(own[4 * i4 + 0], own[4 * i4 + 1],
                               own[4 * i4 + 2], own[4 * i4 + 3]);
        *(float4*)&As[t * LDC + 4 * i4] = v;
    }
    {
        float d0 = 0.f, d1 = 0.f, d2 = 0.f, d3 = 0.f;
        #pragma unroll
        for (int i = 0; i < N; i += 4) {
            d0 = fmaf(own[i + 0], own[i + 0], d0);
            d1 = fmaf(own[i + 1], own[i + 1], d1);
            d2 = fmaf(own[i + 2], own[i + 2], d2);
            d3 = fmaf(own[i + 3], own[i + 3], d3);
        }
        float lam = fmaxf((d0 + d1) + (d2 + d3), 1e-30f);
        lw_s[t] = flog_(lam) * frcp(lam);   // X = sum_k (log l / l) c_k c_k^T
    }
    __syncthreads();

    // ---- X = sum_k lw[k] c_k c_k^T ; lane tile = rows 16ti..+15, cols 4tj..+3
    {
        int ti = t >> 4;     // 0..3
        int tj = t & 15;     // 0..15
        float acc[16][4];
        #pragma unroll
        for (int a2 = 0; a2 < 16; ++a2)
            #pragma unroll
            for (int b2 = 0; b2 < 4; ++b2) acc[a2][b2] = 0.f;

        for (int k = 0; k < N; ++k) {
            float w = lw_s[k];
            const float* ck = &As[k * LDC];
            float4 ub = *(const float4*)&ck[4 * tj];
            ub.x *= w; ub.y *= w; ub.z *= w; ub.w *= w;
            float vb[4] = {ub.x, ub.y, ub.z, ub.w};
            float4 ua0 = *(const float4*)&ck[16 * ti + 0];
            float4 ua1 = *(const float4*)&ck[16 * ti + 4];
            float4 ua2 = *(const float4*)&ck[16 * ti + 8];
            float4 ua3 = *(const float4*)&ck[16 * ti + 12];
            float va[16] = {ua0.x, ua0.y, ua0.z, ua0.w,
                            ua1.x, ua1.y, ua1.z, ua1.w,
                            ua2.x, ua2.y, ua2.z, ua2.w,
                            ua3.x, ua3.y, ua3.z, ua3.w};
            #pragma unroll
            for (int a2 = 0; a2 < 16; ++a2)
                #pragma unroll
                for (int b2 = 0; b2 < 4; ++b2)
                    acc[a2][b2] = fmaf(va[a2], vb[b2], acc[a2][b2]);
        }
        #pragma unroll
        for (int a2 = 0; a2 < 16; ++a2) {
            float4 vout = make_float4(acc[a2][0], acc[a2][1], acc[a2][2], acc[a2][3]);
            ((float4*)O)[(16 * ti + a2) * 16 + tj] = vout;
        }
    }
}

extern "C" void kernel_launch(void* const* d_in, const int* in_sizes, int n_in,
                              void* d_out, int out_size, void* d_ws, size_t ws_size,
                              hipStream_t stream) {
    const float* P = (const float*)d_in[0];
    float* Out = (float*)d_out;
    int nmat = in_sizes[0] / (N * N);    // 8192
    logeig_kernel<<<dim3(nmat), dim3(64), 0, stream>>>(P, Out);
}